// Round 4
// baseline (226.362 us; speedup 1.0000x reference)
//
#include <hip/hip_runtime.h>

// Problem constants (setup_inputs is fixed)
#define BATCH 2
#define NTXT  2048
#define TMED  4
#define MMED  256
#define TM    (TMED * MMED)      // 1024 kv rows per batch
#define DIM   1024
#define NH    16
#define DHD   64
#define KVW   2048               // k|v concatenated width
#define RMAX  256                // max real rows per batch handled by fast path
#define RT    32                 // row-tile parallelism for heavy-path kernels

typedef _Float16 f16x8 __attribute__((ext_vector_type(8)));
typedef float    f32x4 __attribute__((ext_vector_type(4)));

// ---------------------------------------------------------------------------
// K1: blocks 0..1: inclusive scan of locations -> txt_time + segment
//     blocks 2..17: ibar[b,c] = mean over j of image[b,j,c]  (atomics)
// ---------------------------------------------------------------------------
__global__ __launch_bounds__(1024) void k1_scan_ibar(
    const int* __restrict__ loc, const float* __restrict__ image,
    int* __restrict__ tt, int* __restrict__ seg, float* __restrict__ ibar) {
  __shared__ int buf[NTXT];
  __shared__ int s_start, s_end;
  const int idx = blockIdx.x;
  const int tid = threadIdx.x;
  if (idx < BATCH) {
    const int b = idx;
    if (tid == 0) { s_start = NTXT; s_end = NTXT; }
    buf[tid]        = loc[b * NTXT + tid];
    buf[tid + 1024] = loc[b * NTXT + tid + 1024];
    __syncthreads();
    for (int off = 1; off < NTXT; off <<= 1) {
      int a0 = (tid >= off) ? buf[tid - off] : 0;
      int a1 = buf[tid + 1024 - off];
      __syncthreads();
      buf[tid] += a0;
      buf[tid + 1024] += a1;
      __syncthreads();
    }
    const int v0 = buf[tid], v1 = buf[tid + 1024];
    tt[b * NTXT + tid]        = v0;
    tt[b * NTXT + tid + 1024] = v1;
    if (v0 >= 1) atomicMin(&s_start, tid);
    if (v0 >= 5) atomicMin(&s_end, tid);
    if (v1 >= 1) atomicMin(&s_start, tid + 1024);
    if (v1 >= 5) atomicMin(&s_end, tid + 1024);
    __syncthreads();
    if (tid == 0) {
      seg[b * 2]     = s_start;
      seg[b * 2 + 1] = s_end - s_start;
    }
  } else {
    const int j = idx - BATCH;          // 0..15
    const int b = j >> 3, rt = j & 7;   // 8 row-tiles of 128
    const float* p = image + (size_t)(b * TM + rt * 128) * DIM + tid;
    float s = 0.f;
#pragma unroll 4
    for (int r = 0; r < 128; r++) s += p[(size_t)r * DIM];
    atomicAdd(&ibar[b * DIM + tid], s * (1.0f / (float)TM));
  }
}

// ---------------------------------------------------------------------------
// K2: blocks 0..511 : Wkv (K x N f32) -> WkvT (N x K f16) transpose
//     blocks 512..575: LayerNorm of real rows -> tn
//     blocks 576..583: vbar[b,e] = ibar[b,:] @ Wkv[:, DIM+e]   (exact algebra)
// ---------------------------------------------------------------------------
__global__ __launch_bounds__(256) void k2_prep(
    const float* __restrict__ Wkv, const float* __restrict__ text,
    const float* __restrict__ gamma, const float* __restrict__ beta,
    const int* __restrict__ seg, const float* __restrict__ ibar,
    _Float16* __restrict__ WkvT, float* __restrict__ tn,
    float* __restrict__ vbar) {
  __shared__ float tile[64][65];
  __shared__ float red[256];
  const int idx = blockIdx.x;
  const int tid = threadIdx.x;
  if (idx < 512) {
    // ---- transpose+convert ----
    const int k0 = (idx & 15) * 64, n0 = (idx >> 4) * 64;
    const int r = tid >> 4, c4 = (tid & 15) * 4;
#pragma unroll
    for (int i = 0; i < 4; i++) {
      const float4 v = *reinterpret_cast<const float4*>(
          Wkv + (size_t)(k0 + r + i * 16) * KVW + n0 + c4);
      tile[r + i * 16][c4 + 0] = v.x; tile[r + i * 16][c4 + 1] = v.y;
      tile[r + i * 16][c4 + 2] = v.z; tile[r + i * 16][c4 + 3] = v.w;
    }
    __syncthreads();
#pragma unroll
    for (int it = 0; it < 2; it++) {
      const int chunk = it * 256 + tid;
      const int n = chunk >> 3, kc = (chunk & 7) * 8;
      f16x8 h;
#pragma unroll
      for (int j = 0; j < 8; j++) h[j] = (_Float16)tile[kc + j][n];
      *reinterpret_cast<f16x8*>(WkvT + (size_t)(n0 + n) * DIM + k0 + kc) = h;
    }
  } else if (idx < 576) {
    // ---- LayerNorm of real rows ----
    const int j = idx - 512;
    const int b = j >> 5, rt = j & 31;
    const int i0 = seg[b * 2];
    const int cnt = min(seg[b * 2 + 1], RMAX);
    for (int r = rt; r < cnt; r += RT) {
      const float* xrow = text + (size_t)(b * NTXT + i0 + r) * DIM;
      float x[4];
      float s = 0.f;
#pragma unroll
      for (int u = 0; u < 4; u++) { x[u] = xrow[tid + 256 * u]; s += x[u]; }
      red[tid] = s; __syncthreads();
      for (int st = 128; st > 0; st >>= 1) {
        if (tid < st) red[tid] += red[tid + st];
        __syncthreads();
      }
      const float mu = red[0] * (1.0f / DIM); __syncthreads();
      float vs = 0.f;
#pragma unroll
      for (int u = 0; u < 4; u++) { float d = x[u] - mu; vs += d * d; }
      red[tid] = vs; __syncthreads();
      for (int st = 128; st > 0; st >>= 1) {
        if (tid < st) red[tid] += red[tid + st];
        __syncthreads();
      }
      const float rstd = rsqrtf(red[0] * (1.0f / DIM) + 1e-5f); __syncthreads();
      float* trow = tn + (size_t)(b * RMAX + r) * DIM;
#pragma unroll
      for (int u = 0; u < 4; u++) {
        const int c = tid + 256 * u;
        trow[c] = (x[u] - mu) * rstd * gamma[c] + beta[c];
      }
      __syncthreads();
    }
  } else {
    // ---- vbar matvec (fp32 exact) ----
    const int j = idx - 576;            // 0..7
    const int b = j >> 2, et = j & 3;
    const int e = et * 256 + tid;
    const float* vb = ibar + b * DIM;
    float s = 0.f;
    for (int c = 0; c < DIM; c++) s += vb[c] * Wkv[(size_t)c * KVW + DIM + e];
    vbar[b * DIM + e] = s;
  }
}

// ---------------------------------------------------------------------------
// K3: blocks 0..255 : f16 MFMA GEMM kv16 = image @ WkvT^T (128x128, BK=32)
//     blocks 256..271: qproj: qbuf[rows] = tn[rows] @ Wq  (LDS row-chunks)
//     blocks 272..275: obar[b,e] = vbar[b,:] @ Wo[:,e]
// ---------------------------------------------------------------------------
__global__ __launch_bounds__(512) void k3_gemm_qproj_obar(
    const float* __restrict__ image, const _Float16* __restrict__ WkvT,
    const float* __restrict__ Wq, const float* __restrict__ Wo,
    const float* __restrict__ tn, const float* __restrict__ vbar,
    const int* __restrict__ seg, _Float16* __restrict__ kv16,
    float* __restrict__ qbuf, float* __restrict__ obar) {
  __shared__ char smem[49152];
  const int idx = blockIdx.x;
  const int tid = threadIdx.x;
  if (idx < 256) {
    // ---- GEMM ----
    _Float16* As = (_Float16*)smem;          // 128*32
    _Float16* Bs = As + 128 * 32;
    const int lane = tid & 63, wid = tid >> 6;
    const int wm = wid & 3, wn = wid >> 2;
    const int row0 = (idx >> 4) * 128, col0 = (idx & 15) * 128;
    const int srow = tid >> 2, skc = (tid & 3) * 8;
    const int frow = lane & 15, fq = lane >> 4;
    f32x4 acc[2][4] = {};
    for (int k0 = 0; k0 < DIM; k0 += 32) {
      const float* ap = image + (size_t)(row0 + srow) * DIM + k0 + skc;
      const float4 a0 = *reinterpret_cast<const float4*>(ap);
      const float4 a1 = *reinterpret_cast<const float4*>(ap + 4);
      f16x8 av;
      av[0] = (_Float16)a0.x; av[1] = (_Float16)a0.y;
      av[2] = (_Float16)a0.z; av[3] = (_Float16)a0.w;
      av[4] = (_Float16)a1.x; av[5] = (_Float16)a1.y;
      av[6] = (_Float16)a1.z; av[7] = (_Float16)a1.w;
      const f16x8 bv = *reinterpret_cast<const f16x8*>(
          WkvT + (size_t)(col0 + srow) * DIM + k0 + skc);
      __syncthreads();
      *reinterpret_cast<f16x8*>(As + tid * 8) = av;
      *reinterpret_cast<f16x8*>(Bs + tid * 8) = bv;
      __syncthreads();
      f16x8 af[2], bf[4];
#pragma unroll
      for (int mt = 0; mt < 2; mt++)
        af[mt] = *reinterpret_cast<const f16x8*>(
            As + (wm * 32 + mt * 16 + frow) * 32 + fq * 8);
#pragma unroll
      for (int nt = 0; nt < 4; nt++)
        bf[nt] = *reinterpret_cast<const f16x8*>(
            Bs + (wn * 64 + nt * 16 + frow) * 32 + fq * 8);
#pragma unroll
      for (int mt = 0; mt < 2; mt++)
#pragma unroll
        for (int nt = 0; nt < 4; nt++)
          acc[mt][nt] = __builtin_amdgcn_mfma_f32_16x16x32_f16(
              af[mt], bf[nt], acc[mt][nt], 0, 0, 0);
    }
#pragma unroll
    for (int mt = 0; mt < 2; mt++)
#pragma unroll
      for (int nt = 0; nt < 4; nt++) {
        const int col = col0 + wn * 64 + nt * 16 + frow;
#pragma unroll
        for (int r = 0; r < 4; r++) {
          const int row = row0 + wm * 32 + mt * 16 + fq * 4 + r;
          kv16[(size_t)row * KVW + col] = (_Float16)acc[mt][nt][r];
        }
      }
  } else if (idx < 272) {
    // ---- qproj ----
    float* tn_s = (float*)smem;              // 8*1024 f32 = 32 KB
    float* qred = tn_s + 8 * 1024;           // 4*8*128 f32 = 16 KB
    const int j = idx - 256;                 // 0..15
    const int b = j >> 3, nt = j & 7;
    const int n0 = nt * 128;
    const int d0 = tid & 127, g = tid >> 7;
    const int cnt = min(seg[b * 2 + 1], RMAX);
    for (int r0 = 0; r0 < cnt; r0 += 8) {
      const float* src = tn + (size_t)(b * RMAX + r0) * DIM;
      for (int i = tid; i < 8 * 1024; i += 512) tn_s[i] = src[i];
      __syncthreads();
      float acc[8] = {};
      const float* wq = Wq + (size_t)(g * 256) * DIM + n0 + d0;
      for (int c = 0; c < 256; c++) {
        const float w = wq[(size_t)c * DIM];
#pragma unroll
        for (int rr = 0; rr < 8; rr++)
          acc[rr] += tn_s[rr * 1024 + g * 256 + c] * w;
      }
#pragma unroll
      for (int rr = 0; rr < 8; rr++) qred[(g * 8 + rr) * 128 + d0] = acc[rr];
      __syncthreads();
      if (g == 0) {
#pragma unroll
        for (int rr = 0; rr < 8; rr++) {
          if (r0 + rr < cnt) {
            const float s = qred[rr * 128 + d0] + qred[(8 + rr) * 128 + d0] +
                            qred[(16 + rr) * 128 + d0] + qred[(24 + rr) * 128 + d0];
            qbuf[(size_t)(b * RMAX + r0 + rr) * DIM + n0 + d0] = s;
          }
        }
      }
      __syncthreads();
    }
  } else {
    // ---- obar matvec ----
    const int j = idx - 272;                 // 0..3
    const int b = j >> 1, et = j & 1;
    const int e = et * 512 + tid;
    const float* vb = vbar + b * DIM;
    float s = 0.f;
    for (int c = 0; c < DIM; c++) s += vb[c] * Wo[(size_t)c * DIM + e];
    obar[b * DIM + e] = s;
  }
}

// ---------------------------------------------------------------------------
// K4: blocks 0..4095 : fill (zero / obar / fallback)
//     blocks 4096..5119: attnh (q from qbuf, scores, softmax, PV -> oacc)
// ---------------------------------------------------------------------------
__global__ __launch_bounds__(256) void k4_fill_attn(
    const float* __restrict__ text, const _Float16* __restrict__ kv16,
    const float* __restrict__ Wq, const float* __restrict__ Wo,
    const float* __restrict__ gamma, const float* __restrict__ beta,
    const int* __restrict__ tt, const int* __restrict__ seg,
    const float* __restrict__ obar, const float* __restrict__ qbuf,
    float* __restrict__ oacc, float* __restrict__ out) {
  __shared__ float red[256];
  __shared__ float pbuf[256];
  const int idx = blockIdx.x;
  const int tid = threadIdx.x;
  if (idx < BATCH * NTXT) {
    const int b = idx >> 11;
    const int i = idx & (NTXT - 1);
    const int t = tt[b * NTXT + i];
    float* orow = out + (size_t)(b * NTXT + i) * DIM;
    if (t == 0) {
      for (int c = tid; c < DIM; c += 256) orow[c] = 0.f;
      return;
    }
    if (t > TMED) {
      const float* ob = obar + b * DIM;
      for (int c = tid; c < DIM; c += 256) orow[c] = ob[c];
      return;
    }
    if (i - seg[b * 2] < RMAX) return;
    // ---- slow fallback (unreachable for realistic data) ----
    __shared__ float tns[DIM];
    __shared__ float qrow[DIM];
    __shared__ float oaccs[DIM];
    const float* xrow = text + (size_t)(b * NTXT + i) * DIM;
    float x[4];
    float s = 0.f;
#pragma unroll
    for (int u = 0; u < 4; u++) { x[u] = xrow[tid + 256 * u]; s += x[u]; }
    red[tid] = s; __syncthreads();
    for (int st = 128; st > 0; st >>= 1) {
      if (tid < st) red[tid] += red[tid + st];
      __syncthreads();
    }
    const float mu = red[0] * (1.0f / DIM); __syncthreads();
    float vs = 0.f;
#pragma unroll
    for (int u = 0; u < 4; u++) { float d = x[u] - mu; vs += d * d; }
    red[tid] = vs; __syncthreads();
    for (int st = 128; st > 0; st >>= 1) {
      if (tid < st) red[tid] += red[tid + st];
      __syncthreads();
    }
    const float rstd = rsqrtf(red[0] * (1.0f / DIM) + 1e-5f); __syncthreads();
#pragma unroll
    for (int u = 0; u < 4; u++) {
      const int c = tid + 256 * u;
      tns[c] = (x[u] - mu) * rstd * gamma[c] + beta[c];
    }
    __syncthreads();
    {
      float qa[4] = {0.f, 0.f, 0.f, 0.f};
      for (int c = 0; c < DIM; c++) {
        const float tv = tns[c];
        const float* w = Wq + (size_t)c * DIM + tid;
#pragma unroll
        for (int u = 0; u < 4; u++) qa[u] += tv * w[256 * u];
      }
#pragma unroll
      for (int u = 0; u < 4; u++) qrow[tid + 256 * u] = qa[u];
    }
    __syncthreads();
    const size_t kvrow0 = (size_t)(b * TM + (t - 1) * MMED) * KVW;
    const int d0 = tid & 63, g = tid >> 6;
    for (int h = 0; h < NH; h++) {
      const _Float16* krow = kv16 + kvrow0 + (size_t)tid * KVW + h * DHD;
      float sc = 0.f;
#pragma unroll
      for (int d = 0; d < DHD; d++) sc += qrow[h * DHD + d] * (float)krow[d];
      sc *= 0.125f;
      red[tid] = sc; __syncthreads();
      for (int st = 128; st > 0; st >>= 1) {
        if (tid < st) red[tid] = fmaxf(red[tid], red[tid + st]);
        __syncthreads();
      }
      const float mx = red[0]; __syncthreads();
      const float e = __expf(sc - mx);
      red[tid] = e; __syncthreads();
      for (int st = 128; st > 0; st >>= 1) {
        if (tid < st) red[tid] += red[tid + st];
        __syncthreads();
      }
      const float inv = 1.0f / red[0]; __syncthreads();
      pbuf[tid] = e * inv; __syncthreads();
      const _Float16* vbase = kv16 + kvrow0 + (size_t)(g * 64) * KVW + DIM + h * DHD + d0;
      float a = 0.f;
#pragma unroll 8
      for (int jj = 0; jj < 64; jj++) a += pbuf[g * 64 + jj] * (float)vbase[(size_t)jj * KVW];
      red[tid] = a; __syncthreads();
      if (tid < 64)
        oaccs[h * DHD + tid] = red[tid] + red[64 + tid] + red[128 + tid] + red[192 + tid];
      __syncthreads();
    }
    float oa[4] = {0.f, 0.f, 0.f, 0.f};
    for (int c = 0; c < DIM; c++) {
      const float ov = oaccs[c];
      const float* w = Wo + (size_t)c * DIM + tid;
#pragma unroll
      for (int u = 0; u < 4; u++) oa[u] += ov * w[256 * u];
    }
#pragma unroll
    for (int u = 0; u < 4; u++) orow[tid + 256 * u] = oa[u];
  } else {
    // ---- attnh ----
    __shared__ float qs[DHD];
    const int j = idx - BATCH * NTXT;       // 0..1023
    const int h = j & 15, rt = (j >> 4) & 31, b = j >> 9;
    const int i0 = seg[b * 2];
    const int cnt = min(seg[b * 2 + 1], RMAX);
    const int d0 = tid & 63, g = tid >> 6;
    for (int r = rt; r < cnt; r += RT) {
      const int i = i0 + r;
      const int t = tt[b * NTXT + i];       // in [1, TMED]
      if (tid < 64) qs[tid] = qbuf[(size_t)(b * RMAX + r) * DIM + h * DHD + tid];
      __syncthreads();
      const size_t kvrow0 = (size_t)(b * TM + (t - 1) * MMED) * KVW;
      const _Float16* krow = kv16 + kvrow0 + (size_t)tid * KVW + h * DHD;
      float sc = 0.f;
#pragma unroll
      for (int d = 0; d < DHD; d += 8) {
        const f16x8 kk = *reinterpret_cast<const f16x8*>(krow + d);
#pragma unroll
        for (int u = 0; u < 8; u++) sc += qs[d + u] * (float)kk[u];
      }
      sc *= 0.125f;
      red[tid] = sc; __syncthreads();
      for (int st = 128; st > 0; st >>= 1) {
        if (tid < st) red[tid] = fmaxf(red[tid], red[tid + st]);
        __syncthreads();
      }
      const float mx = red[0]; __syncthreads();
      const float e = __expf(sc - mx);
      red[tid] = e; __syncthreads();
      for (int st = 128; st > 0; st >>= 1) {
        if (tid < st) red[tid] += red[tid + st];
        __syncthreads();
      }
      const float inv = 1.0f / red[0]; __syncthreads();
      pbuf[tid] = e * inv; __syncthreads();
      const _Float16* vbase = kv16 + kvrow0 + (size_t)(g * 64) * KVW + DIM + h * DHD + d0;
      float a = 0.f;
#pragma unroll 8
      for (int jj = 0; jj < 64; jj++) a += pbuf[g * 64 + jj] * (float)vbase[(size_t)jj * KVW];
      red[tid] = a; __syncthreads();
      if (tid < 64)
        oacc[(size_t)(b * RMAX + r) * DIM + h * DHD + tid] =
            red[tid] + red[64 + tid] + red[128 + tid] + red[192 + tid];
      __syncthreads();
    }
  }
}

// ---------------------------------------------------------------------------
// K5: output projection for real rows. grid (16, RT, BATCH)
// ---------------------------------------------------------------------------
__global__ __launch_bounds__(256) void k5_oproj(
    const float* __restrict__ oacc, const float* __restrict__ Wo,
    const int* __restrict__ seg, float* __restrict__ out) {
  const int ct = blockIdx.x;
  const int rt = blockIdx.y;
  const int b = blockIdx.z;
  const int i0 = seg[b * 2];
  const int cnt = min(seg[b * 2 + 1], RMAX);
  const int tid = threadIdx.x;
  const int d0 = tid & 63, g = tid >> 6;
  __shared__ float op[4][64];
  for (int r = rt; r < cnt; r += RT) {
    const float* arow = oacc + (size_t)(b * RMAX + r) * DIM;
    const float* wo = Wo + (size_t)(g * 256) * DIM + ct * 64 + d0;
    float s = 0.f;
    for (int c = 0; c < 256; c++) s += arow[g * 256 + c] * wo[(size_t)c * DIM];
    op[g][d0] = s; __syncthreads();
    if (tid < 64)
      out[(size_t)(b * NTXT + i0 + r) * DIM + ct * 64 + tid] =
          op[0][tid] + op[1][tid] + op[2][tid] + op[3][tid];
    __syncthreads();
  }
}

// ---------------------------------------------------------------------------
extern "C" void kernel_launch(void* const* d_in, const int* in_sizes, int n_in,
                              void* d_out, int out_size, void* d_ws, size_t ws_size,
                              hipStream_t stream) {
  const float* text  = (const float*)d_in[0];
  const float* image = (const float*)d_in[1];
  const int*   loc   = (const int*)d_in[2];
  const float* Wq    = (const float*)d_in[3];
  const float* Wkv   = (const float*)d_in[4];
  const float* Wo    = (const float*)d_in[5];
  const float* gamma = (const float*)d_in[6];
  const float* beta  = (const float*)d_in[7];
  float* out = (float*)d_out;

  // ws layout: kv16 (8 MB f16) | WkvT (4 MB f16, aliased by oacc f32 2 MB)
  //            | tn (2 MB) | qbuf (2 MB) | ibar | vbar | obar | tt | seg
  _Float16* kv16 = (_Float16*)d_ws;
  _Float16* WkvT = kv16 + (size_t)BATCH * TM * KVW;
  float*    oacc = (float*)WkvT;                      // alias: k4 > k3 use
  float*    tn   = (float*)(WkvT + (size_t)KVW * DIM);
  float*    qbuf = tn + (size_t)BATCH * RMAX * DIM;
  float*    ibar = qbuf + (size_t)BATCH * RMAX * DIM;
  float*    vbar = ibar + BATCH * DIM;
  float*    obar = vbar + BATCH * DIM;
  int*      tt   = (int*)(obar + BATCH * DIM);
  int*      seg  = tt + BATCH * NTXT;

  hipMemsetAsync(ibar, 0, BATCH * DIM * sizeof(float), stream);
  k1_scan_ibar<<<BATCH + 16, 1024, 0, stream>>>(loc, image, tt, seg, ibar);
  k2_prep<<<584, 256, 0, stream>>>(Wkv, text, gamma, beta, seg, ibar,
                                   WkvT, tn, vbar);
  k3_gemm_qproj_obar<<<276, 512, 0, stream>>>(image, WkvT, Wq, Wo, tn, vbar,
                                              seg, kv16, qbuf, obar);
  k4_fill_attn<<<BATCH * NTXT + NH * RT * BATCH, 256, 0, stream>>>(
      text, kv16, Wq, Wo, gamma, beta, tt, seg, obar, qbuf, oacc, out);
  k5_oproj<<<dim3(16, RT, BATCH), 256, 0, stream>>>(oacc, Wo, seg, out);
}

// Round 5
// 159.264 us; speedup vs baseline: 1.4213x; 1.4213x over previous
//
#include <hip/hip_runtime.h>

// Problem constants (setup_inputs is fixed)
#define BATCH 2
#define NTXT  2048
#define TMED  4
#define MMED  256
#define TM    (TMED * MMED)      // 1024 kv rows per batch
#define DIM   1024
#define NH    16
#define DHD   64
#define KVW   2048               // k|v concatenated width
#define RMAX  256                // max real rows per batch handled by fast path
#define RT    32                 // row-tile parallelism for heavy-path kernels

typedef _Float16 f16x8 __attribute__((ext_vector_type(8)));
typedef float    f32x4 __attribute__((ext_vector_type(4)));

// ---------------------------------------------------------------------------
// K1: blocks 0..1 : inclusive scan of locations -> txt_time + segment
//     blocks 2..17: ibar[b,c] = mean_j image[b,j,c] (atomics) AND
//                   img16 = (f16)image   (fused convert, same pass)
// ---------------------------------------------------------------------------
__global__ __launch_bounds__(1024) void k1_scan_ibar(
    const int* __restrict__ loc, const float* __restrict__ image,
    int* __restrict__ tt, int* __restrict__ seg, float* __restrict__ ibar,
    _Float16* __restrict__ img16) {
  __shared__ int buf[NTXT];
  __shared__ int s_start, s_end;
  const int idx = blockIdx.x;
  const int tid = threadIdx.x;
  if (idx < BATCH) {
    const int b = idx;
    if (tid == 0) { s_start = NTXT; s_end = NTXT; }
    buf[tid]        = loc[b * NTXT + tid];
    buf[tid + 1024] = loc[b * NTXT + tid + 1024];
    __syncthreads();
    for (int off = 1; off < NTXT; off <<= 1) {
      int a0 = (tid >= off) ? buf[tid - off] : 0;
      int a1 = buf[tid + 1024 - off];
      __syncthreads();
      buf[tid] += a0;
      buf[tid + 1024] += a1;
      __syncthreads();
    }
    const int v0 = buf[tid], v1 = buf[tid + 1024];
    tt[b * NTXT + tid]        = v0;
    tt[b * NTXT + tid + 1024] = v1;
    if (v0 >= 1) atomicMin(&s_start, tid);
    if (v0 >= 5) atomicMin(&s_end, tid);
    if (v1 >= 1) atomicMin(&s_start, tid + 1024);
    if (v1 >= 5) atomicMin(&s_end, tid + 1024);
    __syncthreads();
    if (tid == 0) {
      seg[b * 2]     = s_start;
      seg[b * 2 + 1] = s_end - s_start;
    }
  } else {
    const int j = idx - BATCH;          // 0..15
    const int b = j >> 3, rt = j & 7;   // 8 row-tiles of 128
    const size_t base = (size_t)(b * TM + rt * 128) * DIM + tid;
    const float* p = image + base;
    _Float16* q = img16 + base;
    float s = 0.f;
#pragma unroll 4
    for (int r = 0; r < 128; r++) {
      const float v = p[(size_t)r * DIM];
      s += v;
      q[(size_t)r * DIM] = (_Float16)v;
    }
    atomicAdd(&ibar[b * DIM + tid], s * (1.0f / (float)TM));
  }
}

// ---------------------------------------------------------------------------
// K2: blocks 0..511  : Wkv (K x N f32) -> WkvT (N x K f16) transpose
//     blocks 512..575: LayerNorm of real rows -> tn
//     blocks 576..639: vbar[b,e] += ibar[b,c0:c0+128] @ Wkv[c0:c0+128, DIM+e]
//                      (c-chunked, short chains, atomics)
// ---------------------------------------------------------------------------
__global__ __launch_bounds__(256) void k2_prep(
    const float* __restrict__ Wkv, const float* __restrict__ text,
    const float* __restrict__ gamma, const float* __restrict__ beta,
    const int* __restrict__ seg, const float* __restrict__ ibar,
    _Float16* __restrict__ WkvT, float* __restrict__ tn,
    float* __restrict__ vbar) {
  __shared__ float tile[64][65];
  __shared__ float red[256];
  const int idx = blockIdx.x;
  const int tid = threadIdx.x;
  if (idx < 512) {
    // ---- transpose+convert Wkv ----
    const int k0 = (idx & 15) * 64, n0 = (idx >> 4) * 64;
    const int r = tid >> 4, c4 = (tid & 15) * 4;
#pragma unroll
    for (int i = 0; i < 4; i++) {
      const float4 v = *reinterpret_cast<const float4*>(
          Wkv + (size_t)(k0 + r + i * 16) * KVW + n0 + c4);
      tile[r + i * 16][c4 + 0] = v.x; tile[r + i * 16][c4 + 1] = v.y;
      tile[r + i * 16][c4 + 2] = v.z; tile[r + i * 16][c4 + 3] = v.w;
    }
    __syncthreads();
#pragma unroll
    for (int it = 0; it < 2; it++) {
      const int chunk = it * 256 + tid;
      const int n = chunk >> 3, kc = (chunk & 7) * 8;
      f16x8 h;
#pragma unroll
      for (int j = 0; j < 8; j++) h[j] = (_Float16)tile[kc + j][n];
      *reinterpret_cast<f16x8*>(WkvT + (size_t)(n0 + n) * DIM + k0 + kc) = h;
    }
  } else if (idx < 576) {
    // ---- LayerNorm of real rows ----
    const int j = idx - 512;
    const int b = j >> 5, rt = j & 31;
    const int i0 = seg[b * 2];
    const int cnt = min(seg[b * 2 + 1], RMAX);
    for (int r = rt; r < cnt; r += RT) {
      const float* xrow = text + (size_t)(b * NTXT + i0 + r) * DIM;
      float x[4];
      float s = 0.f;
#pragma unroll
      for (int u = 0; u < 4; u++) { x[u] = xrow[tid + 256 * u]; s += x[u]; }
      red[tid] = s; __syncthreads();
      for (int st = 128; st > 0; st >>= 1) {
        if (tid < st) red[tid] += red[tid + st];
        __syncthreads();
      }
      const float mu = red[0] * (1.0f / DIM); __syncthreads();
      float vs = 0.f;
#pragma unroll
      for (int u = 0; u < 4; u++) { float d = x[u] - mu; vs += d * d; }
      red[tid] = vs; __syncthreads();
      for (int st = 128; st > 0; st >>= 1) {
        if (tid < st) red[tid] += red[tid + st];
        __syncthreads();
      }
      const float rstd = rsqrtf(red[0] * (1.0f / DIM) + 1e-5f); __syncthreads();
      float* trow = tn + (size_t)(b * RMAX + r) * DIM;
#pragma unroll
      for (int u = 0; u < 4; u++) {
        const int c = tid + 256 * u;
        trow[c] = (x[u] - mu) * rstd * gamma[c] + beta[c];
      }
      __syncthreads();
    }
  } else {
    // ---- vbar partial matvec (c-chunked) ----
    const int j = idx - 576;            // 0..63
    const int b = j >> 5, et = (j >> 3) & 3, cc = j & 7;
    const int e = et * 256 + tid;
    const int c0 = cc * 128;
    if (tid < 128) red[tid] = ibar[b * DIM + c0 + tid];
    __syncthreads();
    float s = 0.f;
    for (int c = 0; c < 128; c++)
      s += red[c] * Wkv[(size_t)(c0 + c) * KVW + DIM + e];
    atomicAdd(&vbar[b * DIM + e], s);
  }
}

// ---------------------------------------------------------------------------
// K3: blocks 0..255  : f16 MFMA GEMM kv16 = img16 @ WkvT^T (128x128, BK=32)
//     blocks 256..319: qproj partials (c-chunked, r-inner FMA, atomics)
//     blocks 320..351: obar partials  (c-chunked, atomics)
// ---------------------------------------------------------------------------
__global__ __launch_bounds__(512) void k3_gemm_qproj_obar(
    const _Float16* __restrict__ img16, const _Float16* __restrict__ WkvT,
    const float* __restrict__ Wq, const float* __restrict__ Wo,
    const float* __restrict__ tn, const float* __restrict__ vbar,
    const int* __restrict__ seg, _Float16* __restrict__ kv16,
    float* __restrict__ qbuf, float* __restrict__ obar) {
  __shared__ char smem[16384];
  const int idx = blockIdx.x;
  const int tid = threadIdx.x;
  if (idx < 256) {
    // ---- GEMM ----
    _Float16* As = (_Float16*)smem;          // 128*32 f16 = 8 KB
    _Float16* Bs = As + 128 * 32;            // 8 KB
    const int lane = tid & 63, wid = tid >> 6;
    const int wm = wid & 3, wn = wid >> 2;
    const int row0 = (idx >> 4) * 128, col0 = (idx & 15) * 128;
    const int srow = tid >> 2, skc = (tid & 3) * 8;
    const int frow = lane & 15, fq = lane >> 4;
    f32x4 acc[2][4] = {};
    for (int k0 = 0; k0 < DIM; k0 += 32) {
      const f16x8 av = *reinterpret_cast<const f16x8*>(
          img16 + (size_t)(row0 + srow) * DIM + k0 + skc);
      const f16x8 bv = *reinterpret_cast<const f16x8*>(
          WkvT + (size_t)(col0 + srow) * DIM + k0 + skc);
      __syncthreads();
      *reinterpret_cast<f16x8*>(As + tid * 8) = av;
      *reinterpret_cast<f16x8*>(Bs + tid * 8) = bv;
      __syncthreads();
      f16x8 af[2], bf[4];
#pragma unroll
      for (int mt = 0; mt < 2; mt++)
        af[mt] = *reinterpret_cast<const f16x8*>(
            As + (wm * 32 + mt * 16 + frow) * 32 + fq * 8);
#pragma unroll
      for (int nt = 0; nt < 4; nt++)
        bf[nt] = *reinterpret_cast<const f16x8*>(
            Bs + (wn * 64 + nt * 16 + frow) * 32 + fq * 8);
#pragma unroll
      for (int mt = 0; mt < 2; mt++)
#pragma unroll
        for (int nt = 0; nt < 4; nt++)
          acc[mt][nt] = __builtin_amdgcn_mfma_f32_16x16x32_f16(
              af[mt], bf[nt], acc[mt][nt], 0, 0, 0);
    }
#pragma unroll
    for (int mt = 0; mt < 2; mt++)
#pragma unroll
      for (int nt = 0; nt < 4; nt++) {
        const int col = col0 + wn * 64 + nt * 16 + frow;
#pragma unroll
        for (int r = 0; r < 4; r++) {
          const int row = row0 + wm * 32 + mt * 16 + fq * 4 + r;
          kv16[(size_t)row * KVW + col] = (_Float16)acc[mt][nt][r];
        }
      }
  } else if (idx < 320) {
    // ---- qproj: q[r, n0:n0+128] += tn[r, c0:c0+256] @ Wq[c0:c0+256, n] ----
    float* tn_s = (float*)smem;              // 8 rows x 256 c = 8 KB
    const int j = idx - 256;                 // 0..63
    const int b = j >> 5, nt = (j >> 2) & 7, cc = j & 3;
    const int n0 = nt * 128, c0 = cc * 256;
    const int n = tid & 127, cs = tid >> 7;  // 4 c-subchunks of 64
    const int cnt = min(seg[b * 2 + 1], RMAX);
    for (int r0 = 0; r0 < cnt; r0 += 8) {
      const int rows = min(8, cnt - r0);
      for (int i = tid; i < 8 * 256; i += 512) {
        const int r = i >> 8, c = i & 255;
        tn_s[i] = (r < rows) ? tn[(size_t)(b * RMAX + r0 + r) * DIM + c0 + c]
                             : 0.f;
      }
      __syncthreads();
      float acc[8] = {};
      for (int ci = 0; ci < 64; ci++) {
        const int c = cs * 64 + ci;
        const float w = Wq[(size_t)(c0 + c) * DIM + n0 + n];
#pragma unroll
        for (int rr = 0; rr < 8; rr++) acc[rr] += tn_s[rr * 256 + c] * w;
      }
      for (int rr = 0; rr < rows; rr++)
        atomicAdd(&qbuf[(size_t)(b * RMAX + r0 + rr) * DIM + n0 + n], acc[rr]);
      __syncthreads();
    }
  } else {
    // ---- obar: obar[b,e] += vbar[b, c0:c0+128] @ Wo[c0:c0+128, e] ----
    float* vb_s = (float*)smem;              // 128 f32
    const int j = idx - 320;                 // 0..31
    const int b = j >> 4, et = (j >> 3) & 1, cc = j & 7;
    const int e = et * 512 + tid;
    const int c0 = cc * 128;
    if (tid < 128) vb_s[tid] = vbar[b * DIM + c0 + tid];
    __syncthreads();
    float s = 0.f;
    for (int c = 0; c < 128; c++)
      s += vb_s[c] * Wo[(size_t)(c0 + c) * DIM + e];
    atomicAdd(&obar[b * DIM + e], s);
  }
}

// ---------------------------------------------------------------------------
// K4: blocks 0..4095    : fill (zero / obar / fallback)
//     blocks 4096..5119 : attnh (q from qbuf, scores, softmax, PV -> oacc)
// ---------------------------------------------------------------------------
__global__ __launch_bounds__(256) void k4_fill_attn(
    const float* __restrict__ text, const _Float16* __restrict__ kv16,
    const float* __restrict__ Wq, const float* __restrict__ Wo,
    const float* __restrict__ gamma, const float* __restrict__ beta,
    const int* __restrict__ tt, const int* __restrict__ seg,
    const float* __restrict__ obar, const float* __restrict__ qbuf,
    float* __restrict__ oacc, float* __restrict__ out) {
  __shared__ float red[256];
  __shared__ float pbuf[256];
  const int idx = blockIdx.x;
  const int tid = threadIdx.x;
  if (idx < BATCH * NTXT) {
    const int b = idx >> 11;
    const int i = idx & (NTXT - 1);
    const int t = tt[b * NTXT + i];
    float* orow = out + (size_t)(b * NTXT + i) * DIM;
    if (t == 0) {
      for (int c = tid; c < DIM; c += 256) orow[c] = 0.f;
      return;
    }
    if (t > TMED) {
      const float* ob = obar + b * DIM;
      for (int c = tid; c < DIM; c += 256) orow[c] = ob[c];
      return;
    }
    if (i - seg[b * 2] < RMAX) return;
    // ---- slow fallback (unreachable for realistic data) ----
    __shared__ float tns[DIM];
    __shared__ float qrow[DIM];
    __shared__ float oaccs[DIM];
    const float* xrow = text + (size_t)(b * NTXT + i) * DIM;
    float x[4];
    float s = 0.f;
#pragma unroll
    for (int u = 0; u < 4; u++) { x[u] = xrow[tid + 256 * u]; s += x[u]; }
    red[tid] = s; __syncthreads();
    for (int st = 128; st > 0; st >>= 1) {
      if (tid < st) red[tid] += red[tid + st];
      __syncthreads();
    }
    const float mu = red[0] * (1.0f / DIM); __syncthreads();
    float vs = 0.f;
#pragma unroll
    for (int u = 0; u < 4; u++) { float d = x[u] - mu; vs += d * d; }
    red[tid] = vs; __syncthreads();
    for (int st = 128; st > 0; st >>= 1) {
      if (tid < st) red[tid] += red[tid + st];
      __syncthreads();
    }
    const float rstd = rsqrtf(red[0] * (1.0f / DIM) + 1e-5f); __syncthreads();
#pragma unroll
    for (int u = 0; u < 4; u++) {
      const int c = tid + 256 * u;
      tns[c] = (x[u] - mu) * rstd * gamma[c] + beta[c];
    }
    __syncthreads();
    {
      float qa[4] = {0.f, 0.f, 0.f, 0.f};
      for (int c = 0; c < DIM; c++) {
        const float tv = tns[c];
        const float* w = Wq + (size_t)c * DIM + tid;
#pragma unroll
        for (int u = 0; u < 4; u++) qa[u] += tv * w[256 * u];
      }
#pragma unroll
      for (int u = 0; u < 4; u++) qrow[tid + 256 * u] = qa[u];
    }
    __syncthreads();
    const size_t kvrow0 = (size_t)(b * TM + (t - 1) * MMED) * KVW;
    const int d0 = tid & 63, g = tid >> 6;
    for (int h = 0; h < NH; h++) {
      const _Float16* krow = kv16 + kvrow0 + (size_t)tid * KVW + h * DHD;
      float sc = 0.f;
#pragma unroll
      for (int d = 0; d < DHD; d++) sc += qrow[h * DHD + d] * (float)krow[d];
      sc *= 0.125f;
      red[tid] = sc; __syncthreads();
      for (int st = 128; st > 0; st >>= 1) {
        if (tid < st) red[tid] = fmaxf(red[tid], red[tid + st]);
        __syncthreads();
      }
      const float mx = red[0]; __syncthreads();
      const float e = __expf(sc - mx);
      red[tid] = e; __syncthreads();
      for (int st = 128; st > 0; st >>= 1) {
        if (tid < st) red[tid] += red[tid + st];
        __syncthreads();
      }
      const float inv = 1.0f / red[0]; __syncthreads();
      pbuf[tid] = e * inv; __syncthreads();
      const _Float16* vbase = kv16 + kvrow0 + (size_t)(g * 64) * KVW + DIM + h * DHD + d0;
      float a = 0.f;
#pragma unroll 8
      for (int jj = 0; jj < 64; jj++) a += pbuf[g * 64 + jj] * (float)vbase[(size_t)jj * KVW];
      red[tid] = a; __syncthreads();
      if (tid < 64)
        oaccs[h * DHD + tid] = red[tid] + red[64 + tid] + red[128 + tid] + red[192 + tid];
      __syncthreads();
    }
    float oa[4] = {0.f, 0.f, 0.f, 0.f};
    for (int c = 0; c < DIM; c++) {
      const float ov = oaccs[c];
      const float* w = Wo + (size_t)c * DIM + tid;
#pragma unroll
      for (int u = 0; u < 4; u++) oa[u] += ov * w[256 * u];
    }
#pragma unroll
    for (int u = 0; u < 4; u++) orow[tid + 256 * u] = oa[u];
  } else {
    // ---- attnh ----
    __shared__ float qs[DHD];
    const int j = idx - BATCH * NTXT;       // 0..1023
    const int h = j & 15, rt = (j >> 4) & 31, b = j >> 9;
    const int i0 = seg[b * 2];
    const int cnt = min(seg[b * 2 + 1], RMAX);
    const int d0 = tid & 63, g = tid >> 6;
    for (int r = rt; r < cnt; r += RT) {
      const int i = i0 + r;
      const int t = tt[b * NTXT + i];       // in [1, TMED]
      if (tid < 64) qs[tid] = qbuf[(size_t)(b * RMAX + r) * DIM + h * DHD + tid];
      __syncthreads();
      const size_t kvrow0 = (size_t)(b * TM + (t - 1) * MMED) * KVW;
      const _Float16* krow = kv16 + kvrow0 + (size_t)tid * KVW + h * DHD;
      float sc = 0.f;
#pragma unroll
      for (int d = 0; d < DHD; d += 8) {
        const f16x8 kk = *reinterpret_cast<const f16x8*>(krow + d);
#pragma unroll
        for (int u = 0; u < 8; u++) sc += qs[d + u] * (float)kk[u];
      }
      sc *= 0.125f;
      red[tid] = sc; __syncthreads();
      for (int st = 128; st > 0; st >>= 1) {
        if (tid < st) red[tid] = fmaxf(red[tid], red[tid + st]);
        __syncthreads();
      }
      const float mx = red[0]; __syncthreads();
      const float e = __expf(sc - mx);
      red[tid] = e; __syncthreads();
      for (int st = 128; st > 0; st >>= 1) {
        if (tid < st) red[tid] += red[tid + st];
        __syncthreads();
      }
      const float inv = 1.0f / red[0]; __syncthreads();
      pbuf[tid] = e * inv; __syncthreads();
      const _Float16* vbase = kv16 + kvrow0 + (size_t)(g * 64) * KVW + DIM + h * DHD + d0;
      float a = 0.f;
#pragma unroll 8
      for (int jj = 0; jj < 64; jj++) a += pbuf[g * 64 + jj] * (float)vbase[(size_t)jj * KVW];
      red[tid] = a; __syncthreads();
      if (tid < 64)
        oacc[(size_t)(b * RMAX + r) * DIM + h * DHD + tid] =
            red[tid] + red[64 + tid] + red[128 + tid] + red[192 + tid];
      __syncthreads();
    }
  }
}

// ---------------------------------------------------------------------------
// K5: output projection for real rows. grid (16, RT, BATCH)
// ---------------------------------------------------------------------------
__global__ __launch_bounds__(256) void k5_oproj(
    const float* __restrict__ oacc, const float* __restrict__ Wo,
    const int* __restrict__ seg, float* __restrict__ out) {
  const int ct = blockIdx.x;
  const int rt = blockIdx.y;
  const int b = blockIdx.z;
  const int i0 = seg[b * 2];
  const int cnt = min(seg[b * 2 + 1], RMAX);
  const int tid = threadIdx.x;
  const int d0 = tid & 63, g = tid >> 6;
  __shared__ float op[4][64];
  for (int r = rt; r < cnt; r += RT) {
    const float* arow = oacc + (size_t)(b * RMAX + r) * DIM;
    const float* wo = Wo + (size_t)(g * 256) * DIM + ct * 64 + d0;
    float s = 0.f;
    for (int c = 0; c < 256; c++) s += arow[g * 256 + c] * wo[(size_t)c * DIM];
    op[g][d0] = s; __syncthreads();
    if (tid < 64)
      out[(size_t)(b * NTXT + i0 + r) * DIM + ct * 64 + tid] =
          op[0][tid] + op[1][tid] + op[2][tid] + op[3][tid];
    __syncthreads();
  }
}

// ---------------------------------------------------------------------------
extern "C" void kernel_launch(void* const* d_in, const int* in_sizes, int n_in,
                              void* d_out, int out_size, void* d_ws, size_t ws_size,
                              hipStream_t stream) {
  const float* text  = (const float*)d_in[0];
  const float* image = (const float*)d_in[1];
  const int*   loc   = (const int*)d_in[2];
  const float* Wq    = (const float*)d_in[3];
  const float* Wkv   = (const float*)d_in[4];
  const float* Wo    = (const float*)d_in[5];
  const float* gamma = (const float*)d_in[6];
  const float* beta  = (const float*)d_in[7];
  float* out = (float*)d_out;

  // ws layout: kv16 8MB | WkvT 4MB (aliased by oacc 2MB after k3) |
  //            img16 4MB | tn 2MB | [memset: qbuf 2MB | ibar | vbar | obar]
  //            | tt | seg          (~22 MB total)
  _Float16* kv16  = (_Float16*)d_ws;
  _Float16* WkvT  = kv16 + (size_t)BATCH * TM * KVW;
  float*    oacc  = (float*)WkvT;                      // alias: k4/k5 > k3 use
  _Float16* img16 = WkvT + (size_t)KVW * DIM;
  float*    tn    = (float*)(img16 + (size_t)BATCH * TM * DIM);
  float*    qbuf  = tn + (size_t)BATCH * RMAX * DIM;
  float*    ibar  = qbuf + (size_t)BATCH * RMAX * DIM;
  float*    vbar  = ibar + BATCH * DIM;
  float*    obar  = vbar + BATCH * DIM;
  int*      tt    = (int*)(obar + BATCH * DIM);
  int*      seg   = tt + BATCH * NTXT;

  // zero qbuf + ibar + vbar + obar in one contiguous memset
  hipMemsetAsync(qbuf, 0,
                 ((size_t)BATCH * RMAX * DIM + 3 * BATCH * DIM) * sizeof(float),
                 stream);
  k1_scan_ibar<<<BATCH + 16, 1024, 0, stream>>>(loc, image, tt, seg, ibar, img16);
  k2_prep<<<640, 256, 0, stream>>>(Wkv, text, gamma, beta, seg, ibar,
                                   WkvT, tn, vbar);
  k3_gemm_qproj_obar<<<352, 512, 0, stream>>>(img16, WkvT, Wq, Wo, tn, vbar,
                                              seg, kv16, qbuf, obar);
  k4_fill_attn<<<BATCH * NTXT + NH * RT * BATCH, 256, 0, stream>>>(
      text, kv16, Wq, Wo, gamma, beta, tt, seg, obar, qbuf, oacc, out);
  k5_oproj<<<dim3(16, RT, BATCH), 256, 0, stream>>>(oacc, Wo, seg, out);
}